// Round 17
// baseline (220.860 us; speedup 1.0000x reference)
//
#include <hip/hip_runtime.h>
#include <math.h>

#define B_ 32
#define C_ 40000
#define D_ 2048
#define T_SCALE 10.0f
#define P_MARG 0.2f
#define N_MARG 0.3f
#define NSTEP 64              // global k-steps of K=32
#define KSPL 4                // K-split factor (K-chunk = 512 = 16 steps)
#define NCB 625               // column blocks (64 cols each)
#define NBLK (NCB * KSPL)     // 2500 blocks, 256 thr (4 waves)

typedef __attribute__((ext_vector_type(4))) float f32x4;
typedef __fp16 fp16x2 __attribute__((ext_vector_type(2)));
typedef _Float16 f16x2n __attribute__((ext_vector_type(2)));
typedef _Float16 half8_t __attribute__((ext_vector_type(8)));

// ---- workspace layout (in floats) ----
#define OP1_OFF 0                          // out partials ks=1..3 [3][32][C]
#define OP_FLOATS (B_ * C_)
#define NS0_OFF (OP1_OFF + 3 * OP_FLOATS)  // nsims partials ks=0..3 [4][32][C]
#define VR_OFF (NS0_OFF + 4 * OP_FLOATS)   // vrow [C]
#define VR_FLOATS C_
#define SC_OFF (VR_OFF + VR_FLOATS)        // scalars
#define S_HLOSS 0
#define S_THSUM 1
#define S_THCNT 2
#define S_BAD 3
#define S_NTH 4  // 32 floats
#define S_BU 36  // 32 floats
#define SC_FLOATS 128
#define DT_OFF (SC_OFF + SC_FLOATS)        // raw batch dots [32][32]
#define DT_FLOATS (32 * 32)
#define AF_OFF (DT_OFF + DT_FLOATS)        // A f16 frags: 64 steps * 4 frags * 64 lanes * 8
#define AF_FLOATS (NSTEP * 2048 / 2)       // 256KB
#define WS_FLOATS_TOTAL (AF_OFF + AF_FLOATS)

__device__ __forceinline__ float softplus_f(float x) {
    return (x > 0.f) ? (x + log1pf(expf(-x))) : log1pf(expf(x));
}

// pack 2 floats to f16x2 with RTZ (hw packed cvt)
__device__ __forceinline__ unsigned pack_rtz(float x0, float x1) {
    fp16x2 h = __builtin_amdgcn_cvt_pkrtz(x0, x1);
    return __builtin_bit_cast(unsigned, h);
}

// pack 2 floats to f16x2 with RTNE
__device__ __forceinline__ unsigned pack_rtne(float x0, float x1) {
    f16x2n p = {(_Float16)x0, (_Float16)x1};
    return __builtin_bit_cast(unsigned, p);
}

// ---- K0: pack A (rows 0-31 = inputs, 32-63 = V[tgt]) fragment-major, f16 ----
// layout (ushort idx): s*2048 + f*512 + lane*8 + j ; f = 0..3 (16 rows each)
__global__ __launch_bounds__(256) void build_Afrag(const float* __restrict__ in,
                                                   const float* __restrict__ V,
                                                   const int* __restrict__ tgt,
                                                   unsigned short* __restrict__ Af) {
    int s = blockIdx.x;           // 0..63
    int f = threadIdx.x >> 6;     // 0..3
    int l = threadIdx.x & 63;
    int row = f * 16 + (l & 15);
    int k = s * 32 + (l >> 4) * 8;
    const float* src = (row < 32) ? (in + (size_t)row * D_ + k)
                                  : (V + (size_t)tgt[row - 32] * D_ + k);
    f32x4 x0 = *(const f32x4*)src;
    f32x4 x1 = *(const f32x4*)(src + 4);
    uint4 u = make_uint4(pack_rtne(x0[0], x0[1]), pack_rtne(x0[2], x0[3]),
                         pack_rtne(x1[0], x1[1]), pack_rtne(x1[2], x1[3]));
    *(uint4*)(Af + (size_t)s * 2048 + (size_t)f * 512 + (size_t)l * 8) = u;
}

// ---- K1b: raw 32x32 batch dots ----
__global__ __launch_bounds__(256) void sims_dots(const float* __restrict__ in,
                                                 float* __restrict__ dt) {
    __shared__ float part[8][32];
    int i = blockIdx.x;
    int j = threadIdx.x & 31;
    int sl = threadIdx.x >> 5;
    const float4* a4 = (const float4*)(in + (size_t)i * D_ + sl * 256);
    const float4* b4 = (const float4*)(in + (size_t)j * D_ + sl * 256);
    float s = 0.f;
#pragma unroll 4
    for (int k = 0; k < 64; ++k) {
        float4 x = a4[k], y = b4[k];
        s += x.x * y.x + x.y * y.y + x.z * y.z + x.w * y.w;
    }
    part[sl][j] = s;
    __syncthreads();
    if (threadIdx.x < 32) {
        float t = 0.f;
#pragma unroll
        for (int p = 0; p < 8; ++p) t += part[p][threadIdx.x];
        dt[i * 32 + threadIdx.x] = t;
    }
}

// ---- K1c: sims, thresholds, h_loss, n_th_t ----
__global__ __launch_bounds__(1024) void small_finish(const float* __restrict__ in,
                                                     const float* __restrict__ V,
                                                     const int* __restrict__ tgt,
                                                     float* __restrict__ ws) {
    __shared__ float sims[32][33];
    __shared__ float nthr[32], pthr[32];
    __shared__ int ts[32];
    __shared__ float diag[32];
    __shared__ float red[4];
    int tid = threadIdx.x;
    int i = tid >> 5, j = tid & 31;
    const float* dt = ws + DT_OFF;
    if (tid < 32) { ts[tid] = tgt[tid]; diag[tid] = dt[tid * 32 + tid]; }
    if (tid < 4) red[tid] = 0.f;
    __syncthreads();
    float sim = dt[i * 32 + j] * rsqrtf(diag[i] * diag[j]);
    sims[i][j] = sim;
    __syncthreads();
    if (tid < 32) {
        float nmin = 2.f, pmax = -2.f;
        int ti = ts[tid];
        for (int jj = 0; jj < 32; ++jj) {
            bool pos = (ts[jj] == ti) && (jj != tid);
            float v = sims[tid][jj];
            if (pos) { nmin = fminf(nmin, v); pmax = fmaxf(pmax, v); }
        }
        nthr[tid] = nmin - N_MARG;
        pthr[tid] = pmax - P_MARG;
    }
    __syncthreads();
    bool pos = (ts[i] == ts[j]) && (i != j);
    bool neg = (ts[i] != ts[j]);
    if (pos && sim < pthr[i]) { atomicAdd(&red[0], softplus_f(-sim)); atomicAdd(&red[1], 1.f); }
    if (neg && sim > nthr[i]) { atomicAdd(&red[2], softplus_f(sim)); atomicAdd(&red[3], 1.f); }

    const float4* a4 = (const float4*)(in + (size_t)i * D_);
    const float4* v4 = (const float4*)(V + (size_t)ts[i] * D_);
    float sn = 0.f;
    for (int k = j; k < D_ / 4; k += 32) {
        float4 x = a4[k], y = v4[k];
        sn += x.x * y.x + x.y * y.y + x.z * y.z + x.w * y.w;
    }
    for (int off = 16; off > 0; off >>= 1) sn += __shfl_down(sn, off, 32);
    if (j == 0) ws[SC_OFF + S_NTH + i] = sn * rsqrtf(diag[i]) - N_MARG;
    __syncthreads();
    if (tid == 0) {
        float h = 0.f;
        if (red[1] > 0.f) h += red[0] / red[1];
        if (red[3] > 0.f) h += red[2] / red[3];
        ws[SC_OFF + S_HLOSS] = h;
    }
}

// ---- K2: MFMA GEMM, direct register streaming (no LDS, no barriers).
//      Block = 64 cols (4 waves x 16 cols), K-chunk 512 (16 steps), K-split x4.
//      Single-f16: per step 4 A uint4 (L2) + 2 V f32x4 (HBM) + 4 cvt + 4 MFMA.
//      4-step register batches, double-buffered, fully unrolled.
//      __launch_bounds__(256,2): 256-VGPR budget so both batches stay resident.
__global__ __launch_bounds__(256, 2) void gemm_mfma(const float* __restrict__ V,
                                                    const unsigned short* __restrict__ Af,
                                                    float* __restrict__ op0, // d_out+1
                                                    float* __restrict__ ws) {
    const int l = threadIdx.x & 63;
    const int w = threadIdx.x >> 6; // 0..3
    const int ks = blockIdx.x & 3;
    const int cb = blockIdx.x >> 2;
    const int col = l & 15, g = l >> 4;
    const int c = cb * 64 + w * 16 + col;

    const float* vp = V + (size_t)c * D_ + ks * 512 + g * 8;
    const unsigned short* ap = Af + (size_t)(ks * 16) * 2048 + (size_t)l * 8;

    f32x4 z = {0.f, 0.f, 0.f, 0.f};
    f32x4 acc0 = z, acc1 = z, acc2 = z, acc3 = z;
    float vsum = 0.f;

    uint4 Aa[4][4], Ab[4][4];
    f32x4 VaA[4], VbA[4], VaB[4], VbB[4];

#define LOADB(AB, VA, VB, t0)                                      \
    _Pragma("unroll") for (int s = 0; s < 4; ++s) {                \
        const unsigned short* as = ap + (size_t)((t0) + s) * 2048; \
        AB[s][0] = *(const uint4*)(as + 0 * 512);                  \
        AB[s][1] = *(const uint4*)(as + 1 * 512);                  \
        AB[s][2] = *(const uint4*)(as + 2 * 512);                  \
        AB[s][3] = *(const uint4*)(as + 3 * 512);                  \
        VA[s] = *(const f32x4*)(vp + ((t0) + s) * 32);             \
        VB[s] = *(const f32x4*)(vp + ((t0) + s) * 32 + 4);         \
    }

#define COMPB(AB, VA, VB)                                                          \
    _Pragma("unroll") for (int s = 0; s < 4; ++s) {                                \
        f32x4 v0 = VA[s], v1 = VB[s];                                              \
        vsum += v0[0] + v0[1] + v0[2] + v0[3] + v1[0] + v1[1] + v1[2] + v1[3];     \
        uint4 bu = make_uint4(pack_rtz(v0[0], v0[1]), pack_rtz(v0[2], v0[3]),      \
                              pack_rtz(v1[0], v1[1]), pack_rtz(v1[2], v1[3]));     \
        half8_t bh = __builtin_bit_cast(half8_t, bu);                              \
        half8_t A0h = __builtin_bit_cast(half8_t, AB[s][0]);                       \
        half8_t A1h = __builtin_bit_cast(half8_t, AB[s][1]);                       \
        half8_t A2h = __builtin_bit_cast(half8_t, AB[s][2]);                       \
        half8_t A3h = __builtin_bit_cast(half8_t, AB[s][3]);                       \
        acc0 = __builtin_amdgcn_mfma_f32_16x16x32_f16(A0h, bh, acc0, 0, 0, 0);     \
        acc1 = __builtin_amdgcn_mfma_f32_16x16x32_f16(A1h, bh, acc1, 0, 0, 0);     \
        acc2 = __builtin_amdgcn_mfma_f32_16x16x32_f16(A2h, bh, acc2, 0, 0, 0);     \
        acc3 = __builtin_amdgcn_mfma_f32_16x16x32_f16(A3h, bh, acc3, 0, 0, 0);     \
    }

    // 16 steps = 4 batches, software-pipelined 2 deep with static names
    LOADB(Aa, VaA, VbA, 0);
    LOADB(Ab, VaB, VbB, 4);
    COMPB(Aa, VaA, VbA);
    LOADB(Aa, VaA, VbA, 8);
    COMPB(Ab, VaB, VbB);
    LOADB(Ab, VaB, VbB, 12);
    COMPB(Aa, VaA, VbA);
    COMPB(Ab, VaB, VbB);

#undef LOADB
#undef COMPB

    // partial V row sums -> vrow (atomic across K-splits)
    vsum += __shfl_xor(vsum, 16);
    vsum += __shfl_xor(vsum, 32);
    if (g == 0) atomicAdd(&ws[VR_OFF + c], vsum);

    float* op = (ks == 0) ? op0 : (ws + OP1_OFF + (size_t)(ks - 1) * OP_FLOATS);
    float* nsp = ws + NS0_OFF + (size_t)ks * OP_FLOATS;
#pragma unroll
    for (int r = 0; r < 4; ++r) {
        int rr = g * 4 + r;
        op[(size_t)rr * C_ + c] = acc0[r];
        op[(size_t)(16 + rr) * C_ + c] = acc1[r];
        nsp[(size_t)rr * C_ + c] = acc2[r];
        nsp[(size_t)(16 + rr) * C_ + c] = acc3[r];
    }
}

// ---- K3: combine partials: final out (scaled), online lse -> bu, th masked sum ----
__global__ __launch_bounds__(1024) void lse_th_combine(float* __restrict__ out, // d_out+1 (= p_ks0)
                                                       const int* __restrict__ tgt,
                                                       float* __restrict__ ws) {
    int b = blockIdx.x;
    int tid = threadIdx.x;
    __shared__ float sm[1024], ss[1024], sts[1024], stc[1024];
    __shared__ float xt;
    const float* p1 = ws + OP1_OFF + 0 * OP_FLOATS + (size_t)b * C_;
    const float* p2 = ws + OP1_OFF + 1 * OP_FLOATS + (size_t)b * C_;
    const float* p3 = ws + OP1_OFF + 2 * OP_FLOATS + (size_t)b * C_;
    const float* q0 = ws + NS0_OFF + 0 * OP_FLOATS + (size_t)b * C_;
    const float* q1 = ws + NS0_OFF + 1 * OP_FLOATS + (size_t)b * C_;
    const float* q2 = ws + NS0_OFF + 2 * OP_FLOATS + (size_t)b * C_;
    const float* q3 = ws + NS0_OFF + 3 * OP_FLOATS + (size_t)b * C_;
    float* orow = out + (size_t)b * C_;
    float nth = ws[SC_OFF + S_NTH + b];
    int tg = tgt[b];
    float m = -INFINITY, s = 0.f, ts = 0.f, tc = 0.f;
    for (int c = tid; c < C_; c += 1024) {
        float x = (orow[c] + p1[c] + p2[c] + p3[c]) * T_SCALE;
        orow[c] = x;
        if (c == tg) xt = x;
        float mn = fmaxf(m, x);
        s = s * expf(m - mn) + expf(x - mn);
        m = mn;
        float q = q0[c] + q1[c] + q2[c] + q3[c];
        if (q > nth && q < 0.9999f) { ts += softplus_f(q); tc += 1.f; }
    }
    sm[tid] = m; ss[tid] = s; sts[tid] = ts; stc[tid] = tc;
    __syncthreads();
    for (int st2 = 512; st2 > 0; st2 >>= 1) {
        if (tid < st2) {
            float m2 = sm[tid + st2], s2 = ss[tid + st2];
            float M = fmaxf(sm[tid], m2);
            ss[tid] = ss[tid] * expf(sm[tid] - M) + s2 * expf(m2 - M);
            sm[tid] = M;
            sts[tid] += sts[tid + st2];
            stc[tid] += stc[tid + st2];
        }
        __syncthreads();
    }
    if (tid == 0) {
        ws[SC_OFF + S_BU + b] = (sm[0] + logf(ss[0])) - xt;
        if (stc[0] != 0.f) {
            atomicAdd(&ws[SC_OFF + S_THSUM], sts[0]);
            atomicAdd(&ws[SC_OFF + S_THCNT], stc[0]);
        }
    }
}

// ---- K4: active-flag (any zero V row-sum) ----
__global__ __launch_bounds__(256) void vrow_check(const float* __restrict__ ws_c,
                                                  float* __restrict__ ws) {
    int c = blockIdx.x * 256 + threadIdx.x;
    if (c < C_ && ws_c[VR_OFF + c] == 0.0f) ws[SC_OFF + S_BAD] = 1.0f;
}

// ---- K5: combine ----
__global__ void finalize(const float* __restrict__ ws, float* __restrict__ out0) {
    if (threadIdx.x == 0 && blockIdx.x == 0) {
        float bu = 0.f;
        for (int b = 0; b < 32; ++b) bu += ws[SC_OFF + S_BU + b];
        bu /= 32.f;
        float h = ws[SC_OFF + S_HLOSS];
        float th = 0.f;
        float cnt = ws[SC_OFF + S_THCNT];
        if (ws[SC_OFF + S_BAD] == 0.f && cnt > 0.f) th = ws[SC_OFF + S_THSUM] / cnt;
        out0[0] = 1.0f * bu + 1.0f * h + 3.0f * th;
    }
}

extern "C" void kernel_launch(void* const* d_in, const int* in_sizes, int n_in,
                              void* d_out, int out_size, void* d_ws, size_t ws_size,
                              hipStream_t stream) {
    const float* in = (const float*)d_in[0];
    const float* V = (const float*)d_in[1];
    const int* tgt = (const int*)d_in[2];
    float* outp = (float*)d_out;
    float* ws = (float*)d_ws;
    unsigned short* Af = (unsigned short*)(ws + AF_OFF);

    // zero vrow + scalars (contiguous)
    (void)hipMemsetAsync((void*)(ws + VR_OFF), 0,
                         (size_t)(VR_FLOATS + SC_FLOATS) * sizeof(float), stream);

    build_Afrag<<<NSTEP, 256, 0, stream>>>(in, V, tgt, Af);
    sims_dots<<<32, 256, 0, stream>>>(in, ws + DT_OFF);
    small_finish<<<1, 1024, 0, stream>>>(in, V, tgt, ws);

    gemm_mfma<<<NBLK, 256, 0, stream>>>(V, Af, outp + 1, ws);

    lse_th_combine<<<B_, 1024, 0, stream>>>(outp + 1, tgt, ws);
    vrow_check<<<(C_ + 255) / 256, 256, 0, stream>>>(ws, ws);
    finalize<<<1, 64, 0, stream>>>(ws, outp);
}

// Round 18
// 204.755 us; speedup vs baseline: 1.0787x; 1.0787x over previous
//
#include <hip/hip_runtime.h>
#include <math.h>

#define B_ 32
#define C_ 40000
#define D_ 2048
#define T_SCALE 10.0f
#define P_MARG 0.2f
#define N_MARG 0.3f
#define NSTEP 64              // global k-steps of K=32
#define KSPL 4                // K-split factor (K-chunk = 512 = 4 stages of 128)
#define NCB 625               // column blocks (64 cols each)
#define NBLK (NCB * KSPL)     // 2500 blocks, 256 thr (4 waves)

typedef __attribute__((ext_vector_type(4))) float f32x4;
typedef __fp16 fp16x2 __attribute__((ext_vector_type(2)));
typedef _Float16 f16x2n __attribute__((ext_vector_type(2)));
typedef _Float16 half8_t __attribute__((ext_vector_type(8)));

// async global->LDS, 16B per lane; LDS dest = wave-uniform base + lane*16
#define GLL(gsrc, ldst)                                                          \
    __builtin_amdgcn_global_load_lds(                                            \
        (const __attribute__((address_space(1))) unsigned int*)(gsrc),           \
        (__attribute__((address_space(3))) unsigned int*)(ldst), 16, 0, 0)

// ---- workspace layout (in floats) ----
#define OP1_OFF 0                          // out partials ks=1..3 [3][32][C]
#define OP_FLOATS (B_ * C_)
#define NS0_OFF (OP1_OFF + 3 * OP_FLOATS)  // nsims partials ks=0..3 [4][32][C]
#define VR_OFF (NS0_OFF + 4 * OP_FLOATS)   // vrow [C]
#define VR_FLOATS C_
#define SC_OFF (VR_OFF + VR_FLOATS)        // scalars
#define S_HLOSS 0
#define S_THSUM 1
#define S_THCNT 2
#define S_BAD 3
#define S_NTH 4  // 32 floats
#define S_BU 36  // 32 floats
#define SC_FLOATS 128
#define DT_OFF (SC_OFF + SC_FLOATS)        // raw batch dots [32][32]
#define DT_FLOATS (32 * 32)
#define AF_OFF (DT_OFF + DT_FLOATS)        // A f16 frags: 64 steps * 4 frags * 64 lanes * 8
#define AF_FLOATS (NSTEP * 2048 / 2)       // 256KB
#define WS_FLOATS_TOTAL (AF_OFF + AF_FLOATS)

__device__ __forceinline__ float softplus_f(float x) {
    return (x > 0.f) ? (x + log1pf(expf(-x))) : log1pf(expf(x));
}

// pack 2 floats to f16x2 with RTZ (hw packed cvt)
__device__ __forceinline__ unsigned pack_rtz(float x0, float x1) {
    fp16x2 h = __builtin_amdgcn_cvt_pkrtz(x0, x1);
    return __builtin_bit_cast(unsigned, h);
}

// pack 2 floats to f16x2 with RTNE
__device__ __forceinline__ unsigned pack_rtne(float x0, float x1) {
    f16x2n p = {(_Float16)x0, (_Float16)x1};
    return __builtin_bit_cast(unsigned, p);
}

// ---- K0: pack A (rows 0-31 = inputs, 32-63 = V[tgt]) fragment-major, f16 ----
// layout (ushort idx): s*2048 + f*512 + lane*8 + j ; f = 0..3 (16 rows each)
__global__ __launch_bounds__(256) void build_Afrag(const float* __restrict__ in,
                                                   const float* __restrict__ V,
                                                   const int* __restrict__ tgt,
                                                   unsigned short* __restrict__ Af) {
    int s = blockIdx.x;           // 0..63
    int f = threadIdx.x >> 6;     // 0..3
    int l = threadIdx.x & 63;
    int row = f * 16 + (l & 15);
    int k = s * 32 + (l >> 4) * 8;
    const float* src = (row < 32) ? (in + (size_t)row * D_ + k)
                                  : (V + (size_t)tgt[row - 32] * D_ + k);
    f32x4 x0 = *(const f32x4*)src;
    f32x4 x1 = *(const f32x4*)(src + 4);
    uint4 u = make_uint4(pack_rtne(x0[0], x0[1]), pack_rtne(x0[2], x0[3]),
                         pack_rtne(x1[0], x1[1]), pack_rtne(x1[2], x1[3]));
    *(uint4*)(Af + (size_t)s * 2048 + (size_t)f * 512 + (size_t)l * 8) = u;
}

// ---- K1b: raw 32x32 batch dots ----
__global__ __launch_bounds__(256) void sims_dots(const float* __restrict__ in,
                                                 float* __restrict__ dt) {
    __shared__ float part[8][32];
    int i = blockIdx.x;
    int j = threadIdx.x & 31;
    int sl = threadIdx.x >> 5;
    const float4* a4 = (const float4*)(in + (size_t)i * D_ + sl * 256);
    const float4* b4 = (const float4*)(in + (size_t)j * D_ + sl * 256);
    float s = 0.f;
#pragma unroll 4
    for (int k = 0; k < 64; ++k) {
        float4 x = a4[k], y = b4[k];
        s += x.x * y.x + x.y * y.y + x.z * y.z + x.w * y.w;
    }
    part[sl][j] = s;
    __syncthreads();
    if (threadIdx.x < 32) {
        float t = 0.f;
#pragma unroll
        for (int p = 0; p < 8; ++p) t += part[p][threadIdx.x];
        dt[i * 32 + threadIdx.x] = t;
    }
}

// ---- K1c: sims, thresholds, h_loss, n_th_t ----
__global__ __launch_bounds__(1024) void small_finish(const float* __restrict__ in,
                                                     const float* __restrict__ V,
                                                     const int* __restrict__ tgt,
                                                     float* __restrict__ ws) {
    __shared__ float sims[32][33];
    __shared__ float nthr[32], pthr[32];
    __shared__ int ts[32];
    __shared__ float diag[32];
    __shared__ float red[4];
    int tid = threadIdx.x;
    int i = tid >> 5, j = tid & 31;
    const float* dt = ws + DT_OFF;
    if (tid < 32) { ts[tid] = tgt[tid]; diag[tid] = dt[tid * 32 + tid]; }
    if (tid < 4) red[tid] = 0.f;
    __syncthreads();
    float sim = dt[i * 32 + j] * rsqrtf(diag[i] * diag[j]);
    sims[i][j] = sim;
    __syncthreads();
    if (tid < 32) {
        float nmin = 2.f, pmax = -2.f;
        int ti = ts[tid];
        for (int jj = 0; jj < 32; ++jj) {
            bool pos = (ts[jj] == ti) && (jj != tid);
            float v = sims[tid][jj];
            if (pos) { nmin = fminf(nmin, v); pmax = fmaxf(pmax, v); }
        }
        nthr[tid] = nmin - N_MARG;
        pthr[tid] = pmax - P_MARG;
    }
    __syncthreads();
    bool pos = (ts[i] == ts[j]) && (i != j);
    bool neg = (ts[i] != ts[j]);
    if (pos && sim < pthr[i]) { atomicAdd(&red[0], softplus_f(-sim)); atomicAdd(&red[1], 1.f); }
    if (neg && sim > nthr[i]) { atomicAdd(&red[2], softplus_f(sim)); atomicAdd(&red[3], 1.f); }

    const float4* a4 = (const float4*)(in + (size_t)i * D_);
    const float4* v4 = (const float4*)(V + (size_t)ts[i] * D_);
    float sn = 0.f;
    for (int k = j; k < D_ / 4; k += 32) {
        float4 x = a4[k], y = v4[k];
        sn += x.x * y.x + x.y * y.y + x.z * y.z + x.w * y.w;
    }
    for (int off = 16; off > 0; off >>= 1) sn += __shfl_down(sn, off, 32);
    if (j == 0) ws[SC_OFF + S_NTH + i] = sn * rsqrtf(diag[i]) - N_MARG;
    __syncthreads();
    if (tid == 0) {
        float h = 0.f;
        if (red[1] > 0.f) h += red[0] / red[1];
        if (red[3] > 0.f) h += red[2] / red[3];
        ws[SC_OFF + S_HLOSS] = h;
    }
}

// ---- K2: MFMA GEMM, DRAM-page-local V staging.
//      Block = 64 cols (4 waves x 16 private rows), K-chunk 512 (4 stages of 128).
//      Per wave/stage: 8 GLL, each 2 rows x 512B CONTIGUOUS (16B chunks permuted
//      by the XOR swizzle within the 512B window). LDS [16][128] per wave, dbuf.
//      A read directly from L2 (frag-major Af) into registers per step.
//      Single-f16 MFMA: 4 per step. 4 barriers per block total.
__global__ __launch_bounds__(256, 2) void gemm_mfma(const float* __restrict__ V,
                                                    const unsigned short* __restrict__ Af,
                                                    float* __restrict__ op0, // d_out+1
                                                    float* __restrict__ ws) {
    __shared__ float Va[4][16][128]; // 32KB
    __shared__ float Vb[4][16][128]; // 32KB
    const int l = threadIdx.x & 63;
    const int w = threadIdx.x >> 6; // 0..3
    const int ks = blockIdx.x & 3;
    const int cb = blockIdx.x >> 2;
    const int col = l & 15, g = l >> 4;
    const int crow0 = cb * 64 + w * 16;
    const int c = crow0 + col;
    const int lhi = l >> 5;   // 0/1
    const int l31 = l & 31;
    const int c7 = col & 7;

    f32x4 z = {0.f, 0.f, 0.f, 0.f};
    f32x4 acc0 = z, acc1 = z, acc2 = z, acc3 = z;
    float vsum = 0.f;

// stage: 16 rows x 128 floats; GLL j covers rows 2j,2j+1, 512B contiguous each,
// 16B chunks pre-permuted so LDS chunk p of row r holds logical chunk p^(r&7)
#define STAGE_V(VB, stg)                                                          \
    do {                                                                          \
        const size_t kb_ = (size_t)ks * 512 + (size_t)(stg) * 128;                \
        _Pragma("unroll") for (int j = 0; j < 8; ++j) {                           \
            const int r_ = 2 * j + lhi;                                           \
            GLL(V + (size_t)(crow0 + r_) * D_ + kb_ + 4 * (l31 ^ (r_ & 7)),       \
                &VB[w][2 * j][0]);                                                \
        }                                                                         \
    } while (0)

#define COMPUTE(VB, stg)                                                           \
    _Pragma("unroll") for (int s = 0; s < 4; ++s) {                                \
        const int sg = ks * 16 + (stg) * 4 + s;                                    \
        const unsigned short* as_ = Af + (size_t)sg * 2048 + (size_t)l * 8;        \
        uint4 a0 = *(const uint4*)(as_ + 0 * 512);                                 \
        uint4 a1 = *(const uint4*)(as_ + 1 * 512);                                 \
        uint4 a2 = *(const uint4*)(as_ + 2 * 512);                                 \
        uint4 a3 = *(const uint4*)(as_ + 3 * 512);                                 \
        const int cb0 = s * 8 + g * 2;                                             \
        f32x4 v0 = *(const f32x4*)&VB[w][col][4 * (cb0 ^ c7)];                     \
        f32x4 v1 = *(const f32x4*)&VB[w][col][4 * ((cb0 + 1) ^ c7)];               \
        vsum += v0[0] + v0[1] + v0[2] + v0[3] + v1[0] + v1[1] + v1[2] + v1[3];     \
        uint4 bu = make_uint4(pack_rtz(v0[0], v0[1]), pack_rtz(v0[2], v0[3]),      \
                              pack_rtz(v1[0], v1[1]), pack_rtz(v1[2], v1[3]));     \
        half8_t bh = __builtin_bit_cast(half8_t, bu);                              \
        half8_t A0h = __builtin_bit_cast(half8_t, a0);                             \
        half8_t A1h = __builtin_bit_cast(half8_t, a1);                             \
        half8_t A2h = __builtin_bit_cast(half8_t, a2);                             \
        half8_t A3h = __builtin_bit_cast(half8_t, a3);                             \
        acc0 = __builtin_amdgcn_mfma_f32_16x16x32_f16(A0h, bh, acc0, 0, 0, 0);     \
        acc1 = __builtin_amdgcn_mfma_f32_16x16x32_f16(A1h, bh, acc1, 0, 0, 0);     \
        acc2 = __builtin_amdgcn_mfma_f32_16x16x32_f16(A2h, bh, acc2, 0, 0, 0);     \
        acc3 = __builtin_amdgcn_mfma_f32_16x16x32_f16(A3h, bh, acc3, 0, 0, 0);     \
    }

    // 4 stages, 2-phase double buffer, fully unrolled
    STAGE_V(Va, 0);
    __syncthreads();
    STAGE_V(Vb, 1);
    COMPUTE(Va, 0);
    __syncthreads();
    STAGE_V(Va, 2);
    COMPUTE(Vb, 1);
    __syncthreads();
    STAGE_V(Vb, 3);
    COMPUTE(Va, 2);
    __syncthreads();
    COMPUTE(Vb, 3);

#undef STAGE_V
#undef COMPUTE

    // partial V row sums -> vrow (atomic across K-splits)
    vsum += __shfl_xor(vsum, 16);
    vsum += __shfl_xor(vsum, 32);
    if (g == 0) atomicAdd(&ws[VR_OFF + c], vsum);

    float* op = (ks == 0) ? op0 : (ws + OP1_OFF + (size_t)(ks - 1) * OP_FLOATS);
    float* nsp = ws + NS0_OFF + (size_t)ks * OP_FLOATS;
#pragma unroll
    for (int r = 0; r < 4; ++r) {
        int rr = g * 4 + r;
        op[(size_t)rr * C_ + c] = acc0[r];
        op[(size_t)(16 + rr) * C_ + c] = acc1[r];
        nsp[(size_t)rr * C_ + c] = acc2[r];
        nsp[(size_t)(16 + rr) * C_ + c] = acc3[r];
    }
}

// ---- K3: combine partials: final out (scaled), online lse -> bu, th masked sum ----
__global__ __launch_bounds__(1024) void lse_th_combine(float* __restrict__ out, // d_out+1 (= p_ks0)
                                                       const int* __restrict__ tgt,
                                                       float* __restrict__ ws) {
    int b = blockIdx.x;
    int tid = threadIdx.x;
    __shared__ float sm[1024], ss[1024], sts[1024], stc[1024];
    __shared__ float xt;
    const float* p1 = ws + OP1_OFF + 0 * OP_FLOATS + (size_t)b * C_;
    const float* p2 = ws + OP1_OFF + 1 * OP_FLOATS + (size_t)b * C_;
    const float* p3 = ws + OP1_OFF + 2 * OP_FLOATS + (size_t)b * C_;
    const float* q0 = ws + NS0_OFF + 0 * OP_FLOATS + (size_t)b * C_;
    const float* q1 = ws + NS0_OFF + 1 * OP_FLOATS + (size_t)b * C_;
    const float* q2 = ws + NS0_OFF + 2 * OP_FLOATS + (size_t)b * C_;
    const float* q3 = ws + NS0_OFF + 3 * OP_FLOATS + (size_t)b * C_;
    float* orow = out + (size_t)b * C_;
    float nth = ws[SC_OFF + S_NTH + b];
    int tg = tgt[b];
    float m = -INFINITY, s = 0.f, ts = 0.f, tc = 0.f;
    for (int c = tid; c < C_; c += 1024) {
        float x = (orow[c] + p1[c] + p2[c] + p3[c]) * T_SCALE;
        orow[c] = x;
        if (c == tg) xt = x;
        float mn = fmaxf(m, x);
        s = s * expf(m - mn) + expf(x - mn);
        m = mn;
        float q = q0[c] + q1[c] + q2[c] + q3[c];
        if (q > nth && q < 0.9999f) { ts += softplus_f(q); tc += 1.f; }
    }
    sm[tid] = m; ss[tid] = s; sts[tid] = ts; stc[tid] = tc;
    __syncthreads();
    for (int st2 = 512; st2 > 0; st2 >>= 1) {
        if (tid < st2) {
            float m2 = sm[tid + st2], s2 = ss[tid + st2];
            float M = fmaxf(sm[tid], m2);
            ss[tid] = ss[tid] * expf(sm[tid] - M) + s2 * expf(m2 - M);
            sm[tid] = M;
            sts[tid] += sts[tid + st2];
            stc[tid] += stc[tid + st2];
        }
        __syncthreads();
    }
    if (tid == 0) {
        ws[SC_OFF + S_BU + b] = (sm[0] + logf(ss[0])) - xt;
        if (stc[0] != 0.f) {
            atomicAdd(&ws[SC_OFF + S_THSUM], sts[0]);
            atomicAdd(&ws[SC_OFF + S_THCNT], stc[0]);
        }
    }
}

// ---- K4: active-flag (any zero V row-sum) ----
__global__ __launch_bounds__(256) void vrow_check(const float* __restrict__ ws_c,
                                                  float* __restrict__ ws) {
    int c = blockIdx.x * 256 + threadIdx.x;
    if (c < C_ && ws_c[VR_OFF + c] == 0.0f) ws[SC_OFF + S_BAD] = 1.0f;
}

// ---- K5: combine ----
__global__ void finalize(const float* __restrict__ ws, float* __restrict__ out0) {
    if (threadIdx.x == 0 && blockIdx.x == 0) {
        float bu = 0.f;
        for (int b = 0; b < 32; ++b) bu += ws[SC_OFF + S_BU + b];
        bu /= 32.f;
        float h = ws[SC_OFF + S_HLOSS];
        float th = 0.f;
        float cnt = ws[SC_OFF + S_THCNT];
        if (ws[SC_OFF + S_BAD] == 0.f && cnt > 0.f) th = ws[SC_OFF + S_THSUM] / cnt;
        out0[0] = 1.0f * bu + 1.0f * h + 3.0f * th;
    }
}

extern "C" void kernel_launch(void* const* d_in, const int* in_sizes, int n_in,
                              void* d_out, int out_size, void* d_ws, size_t ws_size,
                              hipStream_t stream) {
    const float* in = (const float*)d_in[0];
    const float* V = (const float*)d_in[1];
    const int* tgt = (const int*)d_in[2];
    float* outp = (float*)d_out;
    float* ws = (float*)d_ws;
    unsigned short* Af = (unsigned short*)(ws + AF_OFF);

    // zero vrow + scalars (contiguous)
    (void)hipMemsetAsync((void*)(ws + VR_OFF), 0,
                         (size_t)(VR_FLOATS + SC_FLOATS) * sizeof(float), stream);

    build_Afrag<<<NSTEP, 256, 0, stream>>>(in, V, tgt, Af);
    sims_dots<<<32, 256, 0, stream>>>(in, ws + DT_OFF);
    small_finish<<<1, 1024, 0, stream>>>(in, V, tgt, ws);

    gemm_mfma<<<NBLK, 256, 0, stream>>>(V, Af, outp + 1, ws);

    lse_th_combine<<<B_, 1024, 0, stream>>>(outp + 1, tgt, ws);
    vrow_check<<<(C_ + 255) / 256, 256, 0, stream>>>(ws, ws);
    finalize<<<1, 64, 0, stream>>>(ws, outp);
}